// Round 15
// baseline (652.835 us; speedup 1.0000x reference)
//
#include <hip/hip_runtime.h>
#include <stdint.h>

#define DTv 0.2f

typedef __attribute__((ext_vector_type(8))) short short8;
typedef __attribute__((ext_vector_type(4))) float f32x4;
#define MFMA16(A,B,C) __builtin_amdgcn_mfma_f32_16x16x32_bf16(A,B,C,0,0,0)
#define GLOAD16(gp, lp) __builtin_amdgcn_global_load_lds( \
    (const __attribute__((address_space(1))) void*)(gp), \
    (__attribute__((address_space(3))) void*)(lp), 16, 0, 0)

// ---------------- sc0/sc1 write-through stores (visible at L3 w/o wbl2) ----------------
__device__ __forceinline__ void st_u16_sc(ushort* p, uint v){
  asm volatile("global_store_short %0, %1, off sc0 sc1" :: "v"(p), "v"(v) : "memory");
}
__device__ __forceinline__ void st_u32_sc(uint* p, uint v){
  asm volatile("global_store_dword %0, %1, off sc0 sc1" :: "v"(p), "v"(v) : "memory");
}
__device__ __forceinline__ void st_f32_sc(float* p, float v){
  asm volatile("global_store_dword %0, %1, off sc0 sc1" :: "v"(p), "v"(v) : "memory");
}

// ---------------- threefry2x32, bit-exact to JAX (partitionable) ----------------
__device__ __forceinline__ uint32_t rotl32(uint32_t v, uint32_t r){ return (v<<r)|(v>>(32u-r)); }

__device__ __forceinline__ void tf2x32(uint32_t k0, uint32_t k1, uint32_t& x0, uint32_t& x1){
  const uint32_t k2 = k0 ^ k1 ^ 0x1BD11BDAu;
  x0 += k0; x1 += k1;
#define RND(r) { x0 += x1; x1 = rotl32(x1,(r)); x1 ^= x0; }
  RND(13u) RND(15u) RND(26u) RND(6u)
  x0 += k1; x1 += k2 + 1u;
  RND(17u) RND(29u) RND(16u) RND(24u)
  x0 += k2; x1 += k0 + 2u;
  RND(13u) RND(15u) RND(26u) RND(6u)
  x0 += k0; x1 += k1 + 3u;
  RND(17u) RND(29u) RND(16u) RND(24u)
  x0 += k1; x1 += k2 + 4u;
  RND(13u) RND(15u) RND(26u) RND(6u)
  x0 += k2; x1 += k0 + 5u;
#undef RND
}

__device__ __forceinline__ float u01(uint32_t bits){
  return __uint_as_float((bits >> 9) | 0x3f800000u) - 1.0f;
}

__device__ __forceinline__ void step_keys(int t, uint32_t* K){
  uint32_t c0 = 0u, c1 = (uint32_t)t;
  tf2x32(0u, 42u, c0, c1);
#pragma unroll
  for (int i = 0; i < 3; ++i){
    uint32_t a = 0u, b = (uint32_t)i;
    tf2x32(c0, c1, a, b);
    K[2*i] = a; K[2*i+1] = b;
  }
}

__device__ __forceinline__ ushort f2bf(float f){
  uint32_t u = __float_as_uint(f);
  u += 0x7fffu + ((u >> 16) & 1u);
  return (ushort)(u >> 16);
}
__device__ __forceinline__ float bf2f(ushort h){ return __uint_as_float(((uint32_t)h) << 16); }

// ---------------- D2 = data @ W4^T + b4 (once per launch) ----------------
__global__ __launch_bounds__(256) void d2p_kernel(
    const float* __restrict__ data, const float* __restrict__ W4, float* __restrict__ Pd2)
{
  __shared__ float As[16][64];
  __shared__ float Bs[16][64];
  const int tb = blockIdx.x / 7;
  const int ch = blockIdx.x % 7;
  const int kb = ch * 112;
  const int R0 = (tb >> 4) << 6;
  const int C0 = (tb & 15) << 6;
  const int tid = threadIdx.x;
  const int ty = tid >> 4, tx = tid & 15;
  const int mA = tid >> 2, kqA = (tid & 3) << 2;
  float acc[4][4] = {{0.f}};
  for (int kk = 0; kk < 112; kk += 16){
    const float4 a = *(const float4*)&data[(R0+mA)*784 + kb + kk + kqA];
    As[kqA+0][mA]=a.x; As[kqA+1][mA]=a.y; As[kqA+2][mA]=a.z; As[kqA+3][mA]=a.w;
    const float4 b = *(const float4*)&W4[(C0+mA)*784 + kb + kk + kqA];
    Bs[kqA+0][mA]=b.x; Bs[kqA+1][mA]=b.y; Bs[kqA+2][mA]=b.z; Bs[kqA+3][mA]=b.w;
    __syncthreads();
#pragma unroll
    for (int k=0;k<16;k++){
      const float4 av = *(const float4*)&As[k][ty<<2];
      const float4 bv = *(const float4*)&Bs[k][tx<<2];
      acc[0][0]=fmaf(av.x,bv.x,acc[0][0]); acc[0][1]=fmaf(av.x,bv.y,acc[0][1]);
      acc[0][2]=fmaf(av.x,bv.z,acc[0][2]); acc[0][3]=fmaf(av.x,bv.w,acc[0][3]);
      acc[1][0]=fmaf(av.y,bv.x,acc[1][0]); acc[1][1]=fmaf(av.y,bv.y,acc[1][1]);
      acc[1][2]=fmaf(av.y,bv.z,acc[1][2]); acc[1][3]=fmaf(av.y,bv.w,acc[1][3]);
      acc[2][0]=fmaf(av.z,bv.x,acc[2][0]); acc[2][1]=fmaf(av.z,bv.y,acc[2][1]);
      acc[2][2]=fmaf(av.z,bv.z,acc[2][2]); acc[2][3]=fmaf(av.z,bv.w,acc[2][3]);
      acc[3][0]=fmaf(av.w,bv.x,acc[3][0]); acc[3][1]=fmaf(av.w,bv.y,acc[3][1]);
      acc[3][2]=fmaf(av.w,bv.z,acc[3][2]); acc[3][3]=fmaf(av.w,bv.w,acc[3][3]);
    }
    __syncthreads();
  }
  float* P = Pd2 + ch*262144;
#pragma unroll
  for (int i=0;i<4;i++){
    const int r = R0 + (ty<<2) + i;
    float4 o; float* op=(float*)&o;
#pragma unroll
    for (int j=0;j<4;j++) op[j] = acc[i][j];
    *(float4*)&P[r*1024 + C0 + (tx<<2)] = o;
  }
}

__global__ __launch_bounds__(256) void d2r_kernel(
    const float* __restrict__ Pd2, const float* __restrict__ b4, float* __restrict__ D2)
{
  const int e = (blockIdx.x*256 + threadIdx.x) << 2;
  float4 acc = *(const float4*)&Pd2[e];
#pragma unroll
  for (int p = 1; p < 7; ++p){
    const float4 q = *(const float4*)&Pd2[p*262144 + e];
    acc.x += q.x; acc.y += q.y; acc.z += q.z; acc.w += q.w;
  }
  const float4 bb = *(const float4*)&b4[e & 1023];
  acc.x += bb.x; acc.y += bb.y; acc.z += bb.z; acc.w += bb.w;
  *(float4*)&D2[e] = acc;
}

// ---------------- pairwise alternating sync (relaxed; sc1 data stores) ----------------
__device__ __forceinline__ void arrive(unsigned* xbar, unsigned* cnt, int grp, unsigned a){
  const unsigned old = __hip_atomic_fetch_add(&xbar[grp << 5], 1u,
                        __ATOMIC_RELAXED, __HIP_MEMORY_SCOPE_AGENT);
  if (old == a*32u + 31u)
    __hip_atomic_fetch_add(cnt, 1u, __ATOMIC_RELAXED, __HIP_MEMORY_SCOPE_AGENT);
}
__device__ __forceinline__ void spinwait(unsigned* cnt, unsigned target){
  unsigned it = 0;
  while (__hip_atomic_load(cnt, __ATOMIC_RELAXED, __HIP_MEMORY_SCOPE_AGENT) < target){
    __builtin_amdgcn_s_sleep(1);
    if (++it > (1u<<26)) break;
  }
  __builtin_amdgcn_fence(__ATOMIC_ACQUIRE, "agent");   // one inv per step
}

// ---------------- persistent kernel ----------------
// 256 blocks x 512 threads. bid decode: g2=(bid>>2)&1, sub=(bid>>1)&1,
// coltile=((bid&1)<<5)+(bid>>3). G0 (g2=0): s1 via sp2 bit panel (regs).
// G1 (g2=1): s2 via ah/al gload_lds staging ([kseg][row] layout, lane-linear,
// conflict-free), plus 2 rows of s0 duty each.
__global__ __launch_bounds__(512) void persist_kernel(
    const float* __restrict__ data, const float* __restrict__ s0i,
    const float* __restrict__ s1i, const float* __restrict__ s2i,
    const float* __restrict__ W1g, const float* __restrict__ W2,
    const float* __restrict__ W3, const float* __restrict__ b0g,
    const float* __restrict__ b2g, const float* __restrict__ D2,
    float* __restrict__ sp0A, float* __restrict__ sp0B,
    unsigned* __restrict__ sp1bA, unsigned* __restrict__ sp1bB,
    unsigned* __restrict__ sp2bA, unsigned* __restrict__ sp2bB,
    ushort* __restrict__ ahA, ushort* __restrict__ ahB,
    ushort* __restrict__ alA, ushort* __restrict__ alB,
    float* __restrict__ out, unsigned* __restrict__ bar)
{
  extern __shared__ char lds[];
  short* Bh   = (short*)lds;                 // [kg 128][col 16][8] shorts = 32KB
  short* Bl   = (short*)(lds + 32768);       // 32KB
  short* Abuf = (short*)(lds + 65536);       // 64KB (G1 staging only)
  float* Sst  = (float*)(lds + 131072);      // [128][16] = 8KB
  float* AUX  = (float*)(lds + 139264);      // 8KB: g2? D2 slice : sp0 slice
  float* MISC = (float*)(lds + 147456);      // 2KB
  uint32_t* K  = (uint32_t*)MISC;            // 6
  float* b0s   = MISC + 8;                   // 10
  float* s0st  = MISC + 18;                  // 20
  float* s0red = MISC + 38;                  // 80
  float* b2s   = MISC + 120;                 // 16
  float* W1epi = MISC + 136;                 // 160

  unsigned* xbar = bar;          // 8 counters, 128B apart
  unsigned* cA   = bar + 256;    // G0 group completions (4/iter)
  unsigned* cB   = bar + 320;    // G1 group completions (4/iter)

  const int bid = blockIdx.x, tid = threadIdx.x;
  const int grp = bid & 7;
  const int g2 = (bid >> 2) & 1, sub = (bid >> 1) & 1;
  const int coltile = ((bid & 1) << 5) + (bid >> 3);
  const int cb = coltile << 4;
  const int w = tid >> 6, lane = tid & 63, lr = lane & 15, sl = lane >> 4;
  const int r0s = ((coltile << 1) + sub) << 1;    // G1's two s0 rows

  // ======== preamble ========
  { // B slice (16 cols of W2/W3), split hi/lo bf16
    const float* Wsrc = g2 ? W3 : W2;
    const int row = tid >> 5, seg = tid & 31;
    const float* src = &Wsrc[(cb + row)*1024 + seg*32];
#pragma unroll
    for (int g = 0; g < 4; ++g){
      short8 h8, l8;
#pragma unroll
      for (int j = 0; j < 8; ++j){
        const float f = src[g*8 + j];
        const ushort hh = f2bf(f);
        h8[j] = (short)hh;
        l8[j] = (short)f2bf(f - bf2f(hh));
      }
      const int kg = seg*4 + g;
      *(short8*)&Bh[(kg<<7) + (row<<3)] = h8;
      *(short8*)&Bl[(kg<<7) + (row<<3)] = l8;
    }
  }
  for (int i = tid; i < 160; i += 512) W1epi[i] = W1g[(cb + i/10)*10 + (i%10)];
  float w1c[20];
#pragma unroll
  for (int j = 0; j < 10; ++j){
    w1c[j]      = W1g[tid*10 + j];
    w1c[10 + j] = W1g[(tid + 512)*10 + j];
  }
  {
    const float* Ssrc = g2 ? s2i : s1i;
    for (int idx = tid; idx < 2048; idx += 512){
      const int r = idx >> 4, c = idx & 15;
      Sst[idx] = Ssrc[(((sub<<7)+r)<<10) + cb + c];
    }
    if (g2){
      for (int idx = tid; idx < 2048; idx += 512){
        const int r = idx >> 4, c = idx & 15;
        AUX[idx] = D2[(((sub<<7)+r)<<10) + cb + c];
      }
    }
  }
  if (tid < 10) b0s[tid] = b0g[tid];
  if (g2 && tid < 20) s0st[tid] = s0i[(r0s + tid/10)*10 + (tid%10)];
  if (tid < 16) b2s[tid] = b2g[cb + tid];
  for (int idx = tid; idx < 784; idx += 512)
    out[526848 + bid*784 + idx] = data[bid*784 + idx];
  if (tid == 0) step_keys(0, K);
  __syncthreads();

  // ======== spikes(0): sc1 writes ========
  {
    const uint32_t kk0 = g2 ? K[4] : K[2];
    const uint32_t kk1 = g2 ? K[5] : K[3];
    ushort* sp1u = (ushort*)sp1bA;
    ushort* sp2u = (ushort*)sp2bA;
#pragma unroll
    for (int i2 = 0; i2 < 4; ++i2){
      const int rloc = (w<<4) + (sl<<2) + i2;
      const int R = (sub<<7) + rloc;
      const int e = (R << 10) + cb + lr;
      const float v = fminf(fmaxf(Sst[(rloc<<4) + lr], 0.f), 1.f);
      uint32_t x0 = 0u, x1 = (uint32_t)e;
      tf2x32(kk0, kk1, x0, x1);
      const bool sp = (u01(x0 ^ x1) < v);
      const unsigned long long bt = __ballot(sp ? 1 : 0);
      if (!g2){
        const int hh = (int)f2bf(v);
        const int ll = (int)f2bf(v - bf2f((ushort)hh));
        const int hp = __shfl_down(hh, 1);
        const int lp = __shfl_down(ll, 1);
        if (!(lr & 1)){
          st_u32_sc((uint*)&ahA[e], (uint)(ushort)hh | ((uint)(ushort)hp << 16));
          st_u32_sc((uint*)&alA[e], (uint)(ushort)ll | ((uint)(ushort)lp << 16));
        }
        if (lr == 0) st_u16_sc(&sp1u[R*64 + (cb>>4)], (uint)((bt >> (sl<<4)) & 0xFFFFu));
      } else {
        if (lr == 0) st_u16_sc(&sp2u[R*64 + (cb>>4)], (uint)((bt >> (sl<<4)) & 0xFFFFu));
      }
    }
    if (g2 && tid < 20){
      const float v = fminf(fmaxf(s0st[tid], 0.f), 1.f);
      const int e = (r0s + tid/10)*10 + (tid%10);
      uint32_t x0 = 0u, x1 = (uint32_t)e;
      tf2x32(K[0], K[1], x0, x1);
      st_f32_sc(&sp0A[e], (u01(x0 ^ x1) < v) ? 1.0f : 0.0f);
    }
  }
  asm volatile("s_waitcnt vmcnt(0)" ::: "memory");
  __syncthreads();
  if (tid == 0) arrive(xbar, g2 ? cB : cA, grp, 0u);

  // GEMM constants
  const int r0g = (sub << 7) + (w << 4);
  // staging lane L covers (row = r0g + (L&15), kseg = L>>4) -> LDS slot = L*16B
  // (gload_lds dest is base + lane*16B; the fragment ds_read is then lane-linear,
  //  conflict-free). Global side: 4 lanes/row read 64B contiguous -> coalesced.
  const int gbase = ((r0g + lr) << 10) + (sl << 3);
  const int fragoff = lane << 3;     // shorts
  const int shl = sl << 3;
  short* AW = Abuf + (w << 12);

#pragma unroll 1
  for (int t = 0; t < 30; ++t){
    const int cur = t & 1;
    const float*    sp0c  = cur ? sp0B  : sp0A;   float*    sp0n  = cur ? sp0A  : sp0B;
    const unsigned* sp1bc = cur ? sp1bB : sp1bA;  unsigned* sp1bn = cur ? sp1bA : sp1bB;
    const unsigned* sp2bc = cur ? sp2bB : sp2bA;  unsigned* sp2bn = cur ? sp2bA : sp2bB;
    const ushort*   ahc   = cur ? ahB   : ahA;    ushort*   ahn   = cur ? ahA   : ahB;
    const ushort*   alc   = cur ? alB   : alA;    ushort*   aln   = cur ? alA   : alB;

    if (tid == 0){
      step_keys(t+1, K);
      spinwait(g2 ? cA : cB, 4u*(t+1));   // wait ONLY on the other group
    }
    __syncthreads();

    if (!g2){
      for (int idx = tid; idx < 1280; idx += 512) AUX[idx] = sp0c[sub*1280 + idx];
      __syncthreads();
    } else {
      // ---- s0 duty: rows r0s, r0s+1 ----
#pragma unroll 1
      for (int rr = 0; rr < 2; ++rr){
        const int r = r0s + rr;
        const unsigned* mrow = sp1bc + r*32;
        const unsigned d0 = mrow[tid >> 5];
        const unsigned d1 = mrow[16 + (tid >> 5)];
        const float sv0 = (float)((d0 >> (tid & 31)) & 1u);
        const float sv1 = (float)((d1 >> (tid & 31)) & 1u);
        float a0_[10];
#pragma unroll
        for (int c2 = 0; c2 < 10; ++c2){
          float a = fmaf(sv0, w1c[c2], 0.f);
          a0_[c2] = fmaf(sv1, w1c[10 + c2], a);
        }
#pragma unroll
        for (int c2 = 0; c2 < 10; ++c2){
          float v = a0_[c2];
          v += __shfl_xor(v, 1);  v += __shfl_xor(v, 2);  v += __shfl_xor(v, 4);
          v += __shfl_xor(v, 8);  v += __shfl_xor(v, 16); v += __shfl_xor(v, 32);
          a0_[c2] = v;
        }
        if (lane == 0){
#pragma unroll
          for (int c2 = 0; c2 < 10; ++c2) s0red[w*10 + c2] = a0_[c2];
        }
        __syncthreads();
        if (tid < 10){
          float sum = 0.f;
#pragma unroll
          for (int ww = 0; ww < 8; ++ww) sum += s0red[ww*10 + tid];
          const float s = s0st[rr*10 + tid];
          float nv = s + DTv*(-s + sum + b0s[tid]);
          nv = fminf(fmaxf(nv, 0.f), 1.f);
          s0st[rr*10 + tid] = nv;
          const int e = r*10 + tid;
          uint32_t x0 = 0u, x1 = (uint32_t)e;
          tf2x32(K[0], K[1], x0, x1);
          st_f32_sc(&sp0n[e], (u01(x0 ^ x1) < nv) ? 1.0f : 0.0f);
        }
        __syncthreads();
      }
    }

    // ---- GEMM ----
    f32x4 acc0 = {0.f,0.f,0.f,0.f}, acc1 = {0.f,0.f,0.f,0.f}, acc2 = {0.f,0.f,0.f,0.f};
    if (!g2){
      // A from sp2 bit panel, unpacked in registers (bit-identical to bf16 spikes)
      const unsigned* mrow = sp2bc + (r0g + lr)*32;
      const uint4 m0 = *(const uint4*)(mrow +  0);
      const uint4 m1 = *(const uint4*)(mrow +  4);
      const uint4 m2 = *(const uint4*)(mrow +  8);
      const uint4 m3 = *(const uint4*)(mrow + 12);
      const uint4 m4 = *(const uint4*)(mrow + 16);
      const uint4 m5 = *(const uint4*)(mrow + 20);
      const uint4 m6 = *(const uint4*)(mrow + 24);
      const uint4 m7 = *(const uint4*)(mrow + 28);
#define U0(ks, DW) { \
      const unsigned b_ = ((DW) >> shl) & 0xFFu; \
      short8 a8; \
      a8[0]=(short)(((b_    )&1)?0x3F80:0); a8[1]=(short)(((b_>>1)&1)?0x3F80:0); \
      a8[2]=(short)(((b_>>2)&1)?0x3F80:0); a8[3]=(short)(((b_>>3)&1)?0x3F80:0); \
      a8[4]=(short)(((b_>>4)&1)?0x3F80:0); a8[5]=(short)(((b_>>5)&1)?0x3F80:0); \
      a8[6]=(short)(((b_>>6)&1)?0x3F80:0); a8[7]=(short)(((b_>>7)&1)?0x3F80:0); \
      const int ib = ((((ks)<<2)+sl)<<7) + (lr<<3); \
      const short8 bh8 = *(const short8*)(Bh + ib); \
      const short8 bl8 = *(const short8*)(Bl + ib); \
      acc0 = MFMA16(a8, bh8, acc0); \
      acc1 = MFMA16(a8, bl8, acc1); }
      U0(0,m0.x)  U0(1,m0.y)  U0(2,m0.z)  U0(3,m0.w)
      U0(4,m1.x)  U0(5,m1.y)  U0(6,m1.z)  U0(7,m1.w)
      U0(8,m2.x)  U0(9,m2.y)  U0(10,m2.z) U0(11,m2.w)
      U0(12,m3.x) U0(13,m3.y) U0(14,m3.z) U0(15,m3.w)
      U0(16,m4.x) U0(17,m4.y) U0(18,m4.z) U0(19,m4.w)
      U0(20,m5.x) U0(21,m5.y) U0(22,m5.z) U0(23,m5.w)
      U0(24,m6.x) U0(25,m6.y) U0(26,m6.z) U0(27,m6.w)
      U0(28,m7.x) U0(29,m7.y) U0(30,m7.z) U0(31,m7.w)
#undef U0
    } else {
      const short* Ah0 = (const short*)ahc + gbase;
      const short* Al0 = (const short*)alc + gbase;
#define G1_ISSUE(c) { GLOAD16(Ah0 + ((c)<<5), AW + (((c)&3)<<10)); \
                      GLOAD16(Al0 + ((c)<<5), AW + (((c)&3)<<10) + 512); }
#define G1_ITER(c, vm) { \
      asm volatile("s_waitcnt vmcnt(" #vm ")" ::: "memory"); \
      __builtin_amdgcn_sched_barrier(0); \
      const short8 h8  = *(const short8*)(AW + (((c)&3)<<10) + fragoff); \
      const short8 l8  = *(const short8*)(AW + (((c)&3)<<10) + 512 + fragoff); \
      const int ib = ((((c)<<2)+sl)<<7) + (lr<<3); \
      const short8 bh8 = *(const short8*)(Bh + ib); \
      const short8 bl8 = *(const short8*)(Bl + ib); \
      acc0 = MFMA16(h8, bh8, acc0); \
      acc1 = MFMA16(h8, bl8, acc1); \
      acc2 = MFMA16(l8, bh8, acc2); \
      __builtin_amdgcn_sched_barrier(0); \
      if ((c) < 28) G1_ISSUE((c)+4) }
      G1_ISSUE(0) G1_ISSUE(1) G1_ISSUE(2) G1_ISSUE(3)
      G1_ITER(0,6)  G1_ITER(1,6)  G1_ITER(2,6)  G1_ITER(3,6)
      G1_ITER(4,6)  G1_ITER(5,6)  G1_ITER(6,6)  G1_ITER(7,6)
      G1_ITER(8,6)  G1_ITER(9,6)  G1_ITER(10,6) G1_ITER(11,6)
      G1_ITER(12,6) G1_ITER(13,6) G1_ITER(14,6) G1_ITER(15,6)
      G1_ITER(16,6) G1_ITER(17,6) G1_ITER(18,6) G1_ITER(19,6)
      G1_ITER(20,6) G1_ITER(21,6) G1_ITER(22,6) G1_ITER(23,6)
      G1_ITER(24,6) G1_ITER(25,6) G1_ITER(26,6) G1_ITER(27,6)
      G1_ITER(28,6) G1_ITER(29,4) G1_ITER(30,2) G1_ITER(31,0)
#undef G1_ITER
#undef G1_ISSUE
    }

    // ---- epilogue (exchange writes via sc1) ----
    {
      const bool emit = (t < 29);
      if (!g2){
        const uint32_t kk0 = K[2], kk1 = K[3];
        ushort* sp1u = (ushort*)sp1bn;
#pragma unroll
        for (int i2 = 0; i2 < 4; ++i2){
          const int rloc = (w<<4) + (sl<<2) + i2;
          float v = acc0[i2] + acc1[i2];
          float sm = 0.f;
#pragma unroll
          for (int k2 = 0; k2 < 10; ++k2)
            sm = fmaf(AUX[rloc*10 + k2], W1epi[lr*10 + k2], sm);
          v += b2s[lr] + sm;
          const float s = Sst[(rloc<<4) + lr];
          float nv = s + DTv*(-s + v);
          nv = fminf(fmaxf(nv, 0.f), 1.f);
          Sst[(rloc<<4) + lr] = nv;
          if (emit){
            const int R = (sub<<7) + rloc;
            const int e = (R << 10) + cb + lr;
            uint32_t x0 = 0u, x1 = (uint32_t)e;
            tf2x32(kk0, kk1, x0, x1);
            const bool sp = (u01(x0 ^ x1) < nv);
            const int hh = (int)f2bf(nv);
            const int ll = (int)f2bf(nv - bf2f((ushort)hh));
            const int hp = __shfl_down(hh, 1);
            const int lp = __shfl_down(ll, 1);
            if (!(lr & 1)){
              st_u32_sc((uint*)&ahn[e], (uint)(ushort)hh | ((uint)(ushort)hp << 16));
              st_u32_sc((uint*)&aln[e], (uint)(ushort)ll | ((uint)(ushort)lp << 16));
            }
            const unsigned long long bt = __ballot(sp ? 1 : 0);
            if (lr == 0) st_u16_sc(&sp1u[R*64 + (cb>>4)], (uint)((bt >> (sl<<4)) & 0xFFFFu));
          }
        }
      } else {
        const uint32_t kk0 = K[4], kk1 = K[5];
        ushort* sp2u = (ushort*)sp2bn;
#pragma unroll
        for (int i2 = 0; i2 < 4; ++i2){
          const int rloc = (w<<4) + (sl<<2) + i2;
          float v = acc0[i2] + acc1[i2] + acc2[i2];
          v += AUX[(rloc<<4) + lr];
          const float s = Sst[(rloc<<4) + lr];
          float nv = s + DTv*(-s + v);
          nv = fminf(fmaxf(nv, 0.f), 1.f);
          Sst[(rloc<<4) + lr] = nv;
          if (emit){
            const int R = (sub<<7) + rloc;
            const int e = (R << 10) + cb + lr;
            uint32_t x0 = 0u, x1 = (uint32_t)e;
            tf2x32(kk0, kk1, x0, x1);
            const bool sp = (u01(x0 ^ x1) < nv);
            const unsigned long long bt = __ballot(sp ? 1 : 0);
            if (lr == 0) st_u16_sc(&sp2u[R*64 + (cb>>4)], (uint)((bt >> (sl<<4)) & 0xFFFFu));
          }
        }
      }
    }

    asm volatile("s_waitcnt vmcnt(0)" ::: "memory");
    __syncthreads();
    if (tid == 0 && t < 29) arrive(xbar, g2 ? cB : cA, grp, (unsigned)(t+1));
  }

  // ======== final output ========
  __syncthreads();
  for (int idx = tid; idx < 2048; idx += 512){
    const int r = (sub<<7) + (idx >> 4);
    const int c = cb + (idx & 15);
    out[(g2 ? 264704 : 2560) + (r << 10) + c] = Sst[idx];
  }
  if (g2 && tid < 20) out[(r0s + tid/10)*10 + (tid%10)] = s0st[tid];
}

// ---------------- host ----------------
extern "C" void kernel_launch(void* const* d_in, const int* in_sizes, int n_in,
                              void* d_out, int out_size, void* d_ws, size_t ws_size,
                              hipStream_t stream)
{
  const float* data = (const float*)d_in[0];
  const float* s0i  = (const float*)d_in[1];
  const float* s1i  = (const float*)d_in[2];
  const float* s2i  = (const float*)d_in[3];
  const float* b0   = (const float*)d_in[5];
  const float* W1   = (const float*)d_in[6];
  const float* W2   = (const float*)d_in[7];
  const float* b2   = (const float*)d_in[8];
  const float* W3   = (const float*)d_in[9];
  const float* W4   = (const float*)d_in[10];
  const float* b4   = (const float*)d_in[11];
  float* out = (float*)d_out;
  float* ws  = (float*)d_ws;

  // ws layout (float offsets), ~10.6 MB
  float* sp0A = ws + 0;           // 2560
  float* sp0B = ws + 2560;        // 2560
  float* D2   = ws + 5120;        // 262144
  float* Pd2  = ws + 267264;      // 1835008
  ushort* ahA = (ushort*)(ws + 2102272);   // 262144 ushorts each
  ushort* ahB = (ushort*)(ws + 2233344);
  ushort* alA = (ushort*)(ws + 2364416);
  ushort* alB = (ushort*)(ws + 2495488);
  unsigned* sp1bA = (unsigned*)(ws + 2626560);  // 8192 uints each (32KB)
  unsigned* sp1bB = (unsigned*)(ws + 2634752);
  unsigned* sp2bA = (unsigned*)(ws + 2642944);
  unsigned* sp2bB = (unsigned*)(ws + 2651136);
  unsigned* bar   = (unsigned*)(ws + 2659328);  // xbar(1024B) + cA(+1024) + cB(+1280)

  hipMemsetAsync(bar, 0, 2048, stream);
  d2p_kernel<<<448,256,0,stream>>>(data, W4, Pd2);
  d2r_kernel<<<256,256,0,stream>>>(Pd2, b4, D2);
  persist_kernel<<<256,512,149504,stream>>>(
      data, s0i, s1i, s2i, W1, W2, W3, b0, b2, D2,
      sp0A, sp0B, sp1bA, sp1bB, sp2bA, sp2bB,
      ahA, ahB, alA, alB, out, bar);
}

// Round 16
// 467.345 us; speedup vs baseline: 1.3969x; 1.3969x over previous
//
#include <hip/hip_runtime.h>
#include <stdint.h>

#define DTv 0.2f

typedef __attribute__((ext_vector_type(8))) short short8;
typedef __attribute__((ext_vector_type(4))) float f32x4;
#define MFMA16(A,B,C) __builtin_amdgcn_mfma_f32_16x16x32_bf16(A,B,C,0,0,0)
#define GLOAD16(gp, lp) __builtin_amdgcn_global_load_lds( \
    (const __attribute__((address_space(1))) void*)(gp), \
    (__attribute__((address_space(3))) void*)(lp), 16, 0, 0)

// ---------------- sc0/sc1 write-through stores (visible at L3 w/o wbl2) ----------------
__device__ __forceinline__ void st_u16_sc(ushort* p, uint v){
  asm volatile("global_store_short %0, %1, off sc0 sc1" :: "v"(p), "v"(v) : "memory");
}
__device__ __forceinline__ void st_u32_sc(uint* p, uint v){
  asm volatile("global_store_dword %0, %1, off sc0 sc1" :: "v"(p), "v"(v) : "memory");
}
__device__ __forceinline__ void st_f32_sc(float* p, float v){
  asm volatile("global_store_dword %0, %1, off sc0 sc1" :: "v"(p), "v"(v) : "memory");
}

// ---------------- threefry2x32, bit-exact to JAX (partitionable) ----------------
__device__ __forceinline__ uint32_t rotl32(uint32_t v, uint32_t r){ return (v<<r)|(v>>(32u-r)); }

__device__ __forceinline__ void tf2x32(uint32_t k0, uint32_t k1, uint32_t& x0, uint32_t& x1){
  const uint32_t k2 = k0 ^ k1 ^ 0x1BD11BDAu;
  x0 += k0; x1 += k1;
#define RND(r) { x0 += x1; x1 = rotl32(x1,(r)); x1 ^= x0; }
  RND(13u) RND(15u) RND(26u) RND(6u)
  x0 += k1; x1 += k2 + 1u;
  RND(17u) RND(29u) RND(16u) RND(24u)
  x0 += k2; x1 += k0 + 2u;
  RND(13u) RND(15u) RND(26u) RND(6u)
  x0 += k0; x1 += k1 + 3u;
  RND(17u) RND(29u) RND(16u) RND(24u)
  x0 += k1; x1 += k2 + 4u;
  RND(13u) RND(15u) RND(26u) RND(6u)
  x0 += k2; x1 += k0 + 5u;
#undef RND
}

__device__ __forceinline__ float u01(uint32_t bits){
  return __uint_as_float((bits >> 9) | 0x3f800000u) - 1.0f;
}

__device__ __forceinline__ void step_keys(int t, uint32_t* K){
  uint32_t c0 = 0u, c1 = (uint32_t)t;
  tf2x32(0u, 42u, c0, c1);
#pragma unroll
  for (int i = 0; i < 3; ++i){
    uint32_t a = 0u, b = (uint32_t)i;
    tf2x32(c0, c1, a, b);
    K[2*i] = a; K[2*i+1] = b;
  }
}

__device__ __forceinline__ ushort f2bf(float f){
  uint32_t u = __float_as_uint(f);
  u += 0x7fffu + ((u >> 16) & 1u);
  return (ushort)(u >> 16);
}
__device__ __forceinline__ float bf2f(ushort h){ return __uint_as_float(((uint32_t)h) << 16); }

// ---------------- D2 = data @ W4^T + b4 (once per launch) ----------------
__global__ __launch_bounds__(256) void d2p_kernel(
    const float* __restrict__ data, const float* __restrict__ W4, float* __restrict__ Pd2)
{
  __shared__ float As[16][64];
  __shared__ float Bs[16][64];
  const int tb = blockIdx.x / 7;
  const int ch = blockIdx.x % 7;
  const int kb = ch * 112;
  const int R0 = (tb >> 4) << 6;
  const int C0 = (tb & 15) << 6;
  const int tid = threadIdx.x;
  const int ty = tid >> 4, tx = tid & 15;
  const int mA = tid >> 2, kqA = (tid & 3) << 2;
  float acc[4][4] = {{0.f}};
  for (int kk = 0; kk < 112; kk += 16){
    const float4 a = *(const float4*)&data[(R0+mA)*784 + kb + kk + kqA];
    As[kqA+0][mA]=a.x; As[kqA+1][mA]=a.y; As[kqA+2][mA]=a.z; As[kqA+3][mA]=a.w;
    const float4 b = *(const float4*)&W4[(C0+mA)*784 + kb + kk + kqA];
    Bs[kqA+0][mA]=b.x; Bs[kqA+1][mA]=b.y; Bs[kqA+2][mA]=b.z; Bs[kqA+3][mA]=b.w;
    __syncthreads();
#pragma unroll
    for (int k=0;k<16;k++){
      const float4 av = *(const float4*)&As[k][ty<<2];
      const float4 bv = *(const float4*)&Bs[k][tx<<2];
      acc[0][0]=fmaf(av.x,bv.x,acc[0][0]); acc[0][1]=fmaf(av.x,bv.y,acc[0][1]);
      acc[0][2]=fmaf(av.x,bv.z,acc[0][2]); acc[0][3]=fmaf(av.x,bv.w,acc[0][3]);
      acc[1][0]=fmaf(av.y,bv.x,acc[1][0]); acc[1][1]=fmaf(av.y,bv.y,acc[1][1]);
      acc[1][2]=fmaf(av.y,bv.z,acc[1][2]); acc[1][3]=fmaf(av.y,bv.w,acc[1][3]);
      acc[2][0]=fmaf(av.z,bv.x,acc[2][0]); acc[2][1]=fmaf(av.z,bv.y,acc[2][1]);
      acc[2][2]=fmaf(av.z,bv.z,acc[2][2]); acc[2][3]=fmaf(av.z,bv.w,acc[2][3]);
      acc[3][0]=fmaf(av.w,bv.x,acc[3][0]); acc[3][1]=fmaf(av.w,bv.y,acc[3][1]);
      acc[3][2]=fmaf(av.w,bv.z,acc[3][2]); acc[3][3]=fmaf(av.w,bv.w,acc[3][3]);
    }
    __syncthreads();
  }
  float* P = Pd2 + ch*262144;
#pragma unroll
  for (int i=0;i<4;i++){
    const int r = R0 + (ty<<2) + i;
    float4 o; float* op=(float*)&o;
#pragma unroll
    for (int j=0;j<4;j++) op[j] = acc[i][j];
    *(float4*)&P[r*1024 + C0 + (tx<<2)] = o;
  }
}

__global__ __launch_bounds__(256) void d2r_kernel(
    const float* __restrict__ Pd2, const float* __restrict__ b4, float* __restrict__ D2)
{
  const int e = (blockIdx.x*256 + threadIdx.x) << 2;
  float4 acc = *(const float4*)&Pd2[e];
#pragma unroll
  for (int p = 1; p < 7; ++p){
    const float4 q = *(const float4*)&Pd2[p*262144 + e];
    acc.x += q.x; acc.y += q.y; acc.z += q.z; acc.w += q.w;
  }
  const float4 bb = *(const float4*)&b4[e & 1023];
  acc.x += bb.x; acc.y += bb.y; acc.z += bb.z; acc.w += bb.w;
  *(float4*)&D2[e] = acc;
}

// ---------------- pairwise alternating sync (relaxed; sc1 data stores) ----------------
__device__ __forceinline__ void arrive(unsigned* xbar, unsigned* cnt, int grp, unsigned a){
  const unsigned old = __hip_atomic_fetch_add(&xbar[grp << 5], 1u,
                        __ATOMIC_RELAXED, __HIP_MEMORY_SCOPE_AGENT);
  if (old == a*32u + 31u)
    __hip_atomic_fetch_add(cnt, 1u, __ATOMIC_RELAXED, __HIP_MEMORY_SCOPE_AGENT);
}
__device__ __forceinline__ void spinwait(unsigned* cnt, unsigned target){
  unsigned it = 0;
  while (__hip_atomic_load(cnt, __ATOMIC_RELAXED, __HIP_MEMORY_SCOPE_AGENT) < target){
    __builtin_amdgcn_s_sleep(2);
    if (++it > (1u<<26)) break;
  }
  __builtin_amdgcn_fence(__ATOMIC_ACQUIRE, "agent");   // one inv per step
}

// ---------------- persistent kernel ----------------
// 256 blocks x 512 threads. bid decode: g2=(bid>>2)&1, sub=(bid>>1)&1,
// coltile=((bid&1)<<5)+(bid>>3). G0 (g2=0): s1 via sp2 bit panel (regs).
// G1 (g2=1): s2 via ah/al gload_lds staging (r13 layout: 4 lanes/row, XOR-kseg
// permute -> 4 cachelines per 16-lane coalescing group), + 2 rows s0 duty.
// Tweak vs r13: G1's first 8 prefetches issued BEFORE s0 duty (latency hidden).
__global__ __launch_bounds__(512) void persist_kernel(
    const float* __restrict__ data, const float* __restrict__ s0i,
    const float* __restrict__ s1i, const float* __restrict__ s2i,
    const float* __restrict__ W1g, const float* __restrict__ W2,
    const float* __restrict__ W3, const float* __restrict__ b0g,
    const float* __restrict__ b2g, const float* __restrict__ D2,
    float* __restrict__ sp0A, float* __restrict__ sp0B,
    unsigned* __restrict__ sp1bA, unsigned* __restrict__ sp1bB,
    unsigned* __restrict__ sp2bA, unsigned* __restrict__ sp2bB,
    ushort* __restrict__ ahA, ushort* __restrict__ ahB,
    ushort* __restrict__ alA, ushort* __restrict__ alB,
    float* __restrict__ out, unsigned* __restrict__ bar)
{
  extern __shared__ char lds[];
  short* Bh   = (short*)lds;                 // [kg 128][col 16][8] shorts = 32KB
  short* Bl   = (short*)(lds + 32768);       // 32KB
  short* Abuf = (short*)(lds + 65536);       // 64KB (G1 staging only)
  float* Sst  = (float*)(lds + 131072);      // [128][16] = 8KB
  float* AUX  = (float*)(lds + 139264);      // 8KB: g2? D2 slice : sp0 slice
  float* MISC = (float*)(lds + 147456);      // 2KB
  uint32_t* K  = (uint32_t*)MISC;            // 6
  float* b0s   = MISC + 8;                   // 10
  float* s0st  = MISC + 18;                  // 20
  float* s0red = MISC + 38;                  // 80
  float* b2s   = MISC + 120;                 // 16
  float* W1epi = MISC + 136;                 // 160

  unsigned* xbar = bar;          // 8 counters, 128B apart
  unsigned* cA   = bar + 256;    // G0 group completions (4/iter)
  unsigned* cB   = bar + 320;    // G1 group completions (4/iter)

  const int bid = blockIdx.x, tid = threadIdx.x;
  const int grp = bid & 7;
  const int g2 = (bid >> 2) & 1, sub = (bid >> 1) & 1;
  const int coltile = ((bid & 1) << 5) + (bid >> 3);
  const int cb = coltile << 4;
  const int w = tid >> 6, lane = tid & 63, lr = lane & 15, sl = lane >> 4;
  const int r0s = ((coltile << 1) + sub) << 1;    // G1's two s0 rows

  // ======== preamble ========
  { // B slice (16 cols of W2/W3), split hi/lo bf16
    const float* Wsrc = g2 ? W3 : W2;
    const int row = tid >> 5, seg = tid & 31;
    const float* src = &Wsrc[(cb + row)*1024 + seg*32];
#pragma unroll
    for (int g = 0; g < 4; ++g){
      short8 h8, l8;
#pragma unroll
      for (int j = 0; j < 8; ++j){
        const float f = src[g*8 + j];
        const ushort hh = f2bf(f);
        h8[j] = (short)hh;
        l8[j] = (short)f2bf(f - bf2f(hh));
      }
      const int kg = seg*4 + g;
      *(short8*)&Bh[(kg<<7) + (row<<3)] = h8;
      *(short8*)&Bl[(kg<<7) + (row<<3)] = l8;
    }
  }
  for (int i = tid; i < 160; i += 512) W1epi[i] = W1g[(cb + i/10)*10 + (i%10)];
  float w1c[20];
#pragma unroll
  for (int j = 0; j < 10; ++j){
    w1c[j]      = W1g[tid*10 + j];
    w1c[10 + j] = W1g[(tid + 512)*10 + j];
  }
  {
    const float* Ssrc = g2 ? s2i : s1i;
    for (int idx = tid; idx < 2048; idx += 512){
      const int r = idx >> 4, c = idx & 15;
      Sst[idx] = Ssrc[(((sub<<7)+r)<<10) + cb + c];
    }
    if (g2){
      for (int idx = tid; idx < 2048; idx += 512){
        const int r = idx >> 4, c = idx & 15;
        AUX[idx] = D2[(((sub<<7)+r)<<10) + cb + c];
      }
    }
  }
  if (tid < 10) b0s[tid] = b0g[tid];
  if (g2 && tid < 20) s0st[tid] = s0i[(r0s + tid/10)*10 + (tid%10)];
  if (tid < 16) b2s[tid] = b2g[cb + tid];
  for (int idx = tid; idx < 784; idx += 512)
    out[526848 + bid*784 + idx] = data[bid*784 + idx];
  if (tid == 0) step_keys(0, K);
  __syncthreads();

  // ======== spikes(0): sc1 writes ========
  {
    const uint32_t kk0 = g2 ? K[4] : K[2];
    const uint32_t kk1 = g2 ? K[5] : K[3];
    ushort* sp1u = (ushort*)sp1bA;
    ushort* sp2u = (ushort*)sp2bA;
#pragma unroll
    for (int i2 = 0; i2 < 4; ++i2){
      const int rloc = (w<<4) + (sl<<2) + i2;
      const int R = (sub<<7) + rloc;
      const int e = (R << 10) + cb + lr;
      const float v = fminf(fmaxf(Sst[(rloc<<4) + lr], 0.f), 1.f);
      uint32_t x0 = 0u, x1 = (uint32_t)e;
      tf2x32(kk0, kk1, x0, x1);
      const bool sp = (u01(x0 ^ x1) < v);
      const unsigned long long bt = __ballot(sp ? 1 : 0);
      if (!g2){
        const int hh = (int)f2bf(v);
        const int ll = (int)f2bf(v - bf2f((ushort)hh));
        const int hp = __shfl_down(hh, 1);
        const int lp = __shfl_down(ll, 1);
        if (!(lr & 1)){
          st_u32_sc((uint*)&ahA[e], (uint)(ushort)hh | ((uint)(ushort)hp << 16));
          st_u32_sc((uint*)&alA[e], (uint)(ushort)ll | ((uint)(ushort)lp << 16));
        }
        if (lr == 0) st_u16_sc(&sp1u[R*64 + (cb>>4)], (uint)((bt >> (sl<<4)) & 0xFFFFu));
      } else {
        if (lr == 0) st_u16_sc(&sp2u[R*64 + (cb>>4)], (uint)((bt >> (sl<<4)) & 0xFFFFu));
      }
    }
    if (g2 && tid < 20){
      const float v = fminf(fmaxf(s0st[tid], 0.f), 1.f);
      const int e = (r0s + tid/10)*10 + (tid%10);
      uint32_t x0 = 0u, x1 = (uint32_t)e;
      tf2x32(K[0], K[1], x0, x1);
      st_f32_sc(&sp0A[e], (u01(x0 ^ x1) < v) ? 1.0f : 0.0f);
    }
  }
  asm volatile("s_waitcnt vmcnt(0)" ::: "memory");
  __syncthreads();
  if (tid == 0) arrive(xbar, g2 ? cB : cA, grp, 0u);

  // GEMM constants (r13 mapping)
  const int r0g = (sub << 7) + (w << 4);
  const int gbase = ((r0g + (lane >> 2)) << 10) + ((((lane & 3) ^ ((lane >> 2) & 3))) << 3);
  const int fragoff = (lr << 5) + ((sl ^ (lr & 3)) << 3);
  const int shl = sl << 3;
  short* AW = Abuf + (w << 12);

#pragma unroll 1
  for (int t = 0; t < 30; ++t){
    const int cur = t & 1;
    const float*    sp0c  = cur ? sp0B  : sp0A;   float*    sp0n  = cur ? sp0A  : sp0B;
    const unsigned* sp1bc = cur ? sp1bB : sp1bA;  unsigned* sp1bn = cur ? sp1bA : sp1bB;
    const unsigned* sp2bc = cur ? sp2bB : sp2bA;  unsigned* sp2bn = cur ? sp2bA : sp2bB;
    const ushort*   ahc   = cur ? ahB   : ahA;    ushort*   ahn   = cur ? ahA   : ahB;
    const ushort*   alc   = cur ? alB   : alA;    ushort*   aln   = cur ? alA   : alB;

    if (tid == 0){
      step_keys(t+1, K);
      spinwait(g2 ? cA : cB, 4u*(t+1));   // wait ONLY on the other group
    }
    __syncthreads();

    const short* Ah0 = (const short*)ahc + gbase;
    const short* Al0 = (const short*)alc + gbase;
#define G1_ISSUE(c) { GLOAD16(Ah0 + ((c)<<5), AW + (((c)&3)<<10)); \
                      GLOAD16(Al0 + ((c)<<5), AW + (((c)&3)<<10) + 512); }

    if (!g2){
      for (int idx = tid; idx < 1280; idx += 512) AUX[idx] = sp0c[sub*1280 + idx];
      __syncthreads();
    } else {
      // prefetch first 4 chunks NOW; s0 duty hides their L3 latency
      G1_ISSUE(0) G1_ISSUE(1) G1_ISSUE(2) G1_ISSUE(3)
      // ---- s0 duty: rows r0s, r0s+1 ----
#pragma unroll 1
      for (int rr = 0; rr < 2; ++rr){
        const int r = r0s + rr;
        const unsigned* mrow = sp1bc + r*32;
        const unsigned d0 = mrow[tid >> 5];
        const unsigned d1 = mrow[16 + (tid >> 5)];
        const float sv0 = (float)((d0 >> (tid & 31)) & 1u);
        const float sv1 = (float)((d1 >> (tid & 31)) & 1u);
        float a0_[10];
#pragma unroll
        for (int c2 = 0; c2 < 10; ++c2){
          float a = fmaf(sv0, w1c[c2], 0.f);
          a0_[c2] = fmaf(sv1, w1c[10 + c2], a);
        }
#pragma unroll
        for (int c2 = 0; c2 < 10; ++c2){
          float v = a0_[c2];
          v += __shfl_xor(v, 1);  v += __shfl_xor(v, 2);  v += __shfl_xor(v, 4);
          v += __shfl_xor(v, 8);  v += __shfl_xor(v, 16); v += __shfl_xor(v, 32);
          a0_[c2] = v;
        }
        if (lane == 0){
#pragma unroll
          for (int c2 = 0; c2 < 10; ++c2) s0red[w*10 + c2] = a0_[c2];
        }
        __syncthreads();
        if (tid < 10){
          float sum = 0.f;
#pragma unroll
          for (int ww = 0; ww < 8; ++ww) sum += s0red[ww*10 + tid];
          const float s = s0st[rr*10 + tid];
          float nv = s + DTv*(-s + sum + b0s[tid]);
          nv = fminf(fmaxf(nv, 0.f), 1.f);
          s0st[rr*10 + tid] = nv;
          const int e = r*10 + tid;
          uint32_t x0 = 0u, x1 = (uint32_t)e;
          tf2x32(K[0], K[1], x0, x1);
          st_f32_sc(&sp0n[e], (u01(x0 ^ x1) < nv) ? 1.0f : 0.0f);
        }
        __syncthreads();
      }
    }

    // ---- GEMM ----
    f32x4 acc0 = {0.f,0.f,0.f,0.f}, acc1 = {0.f,0.f,0.f,0.f}, acc2 = {0.f,0.f,0.f,0.f};
    if (!g2){
      // A from sp2 bit panel, unpacked in registers (bit-identical to bf16 spikes)
      const unsigned* mrow = sp2bc + (r0g + lr)*32;
      const uint4 m0 = *(const uint4*)(mrow +  0);
      const uint4 m1 = *(const uint4*)(mrow +  4);
      const uint4 m2 = *(const uint4*)(mrow +  8);
      const uint4 m3 = *(const uint4*)(mrow + 12);
      const uint4 m4 = *(const uint4*)(mrow + 16);
      const uint4 m5 = *(const uint4*)(mrow + 20);
      const uint4 m6 = *(const uint4*)(mrow + 24);
      const uint4 m7 = *(const uint4*)(mrow + 28);
#define U0(ks, DW) { \
      const unsigned b_ = ((DW) >> shl) & 0xFFu; \
      short8 a8; \
      a8[0]=(short)(((b_    )&1)?0x3F80:0); a8[1]=(short)(((b_>>1)&1)?0x3F80:0); \
      a8[2]=(short)(((b_>>2)&1)?0x3F80:0); a8[3]=(short)(((b_>>3)&1)?0x3F80:0); \
      a8[4]=(short)(((b_>>4)&1)?0x3F80:0); a8[5]=(short)(((b_>>5)&1)?0x3F80:0); \
      a8[6]=(short)(((b_>>6)&1)?0x3F80:0); a8[7]=(short)(((b_>>7)&1)?0x3F80:0); \
      const int ib = ((((ks)<<2)+sl)<<7) + (lr<<3); \
      const short8 bh8 = *(const short8*)(Bh + ib); \
      const short8 bl8 = *(const short8*)(Bl + ib); \
      acc0 = MFMA16(a8, bh8, acc0); \
      acc1 = MFMA16(a8, bl8, acc1); }
      U0(0,m0.x)  U0(1,m0.y)  U0(2,m0.z)  U0(3,m0.w)
      U0(4,m1.x)  U0(5,m1.y)  U0(6,m1.z)  U0(7,m1.w)
      U0(8,m2.x)  U0(9,m2.y)  U0(10,m2.z) U0(11,m2.w)
      U0(12,m3.x) U0(13,m3.y) U0(14,m3.z) U0(15,m3.w)
      U0(16,m4.x) U0(17,m4.y) U0(18,m4.z) U0(19,m4.w)
      U0(20,m5.x) U0(21,m5.y) U0(22,m5.z) U0(23,m5.w)
      U0(24,m6.x) U0(25,m6.y) U0(26,m6.z) U0(27,m6.w)
      U0(28,m7.x) U0(29,m7.y) U0(30,m7.z) U0(31,m7.w)
#undef U0
    } else {
#define G1_ITER(c, vm) { \
      asm volatile("s_waitcnt vmcnt(" #vm ")" ::: "memory"); \
      __builtin_amdgcn_sched_barrier(0); \
      const short8 h8  = *(const short8*)(AW + (((c)&3)<<10) + fragoff); \
      const short8 l8  = *(const short8*)(AW + (((c)&3)<<10) + 512 + fragoff); \
      const int ib = ((((c)<<2)+sl)<<7) + (lr<<3); \
      const short8 bh8 = *(const short8*)(Bh + ib); \
      const short8 bl8 = *(const short8*)(Bl + ib); \
      acc0 = MFMA16(h8, bh8, acc0); \
      acc1 = MFMA16(h8, bl8, acc1); \
      acc2 = MFMA16(l8, bh8, acc2); \
      __builtin_amdgcn_sched_barrier(0); \
      if ((c) < 28) G1_ISSUE((c)+4) }
      G1_ITER(0,6)  G1_ITER(1,6)  G1_ITER(2,6)  G1_ITER(3,6)
      G1_ITER(4,6)  G1_ITER(5,6)  G1_ITER(6,6)  G1_ITER(7,6)
      G1_ITER(8,6)  G1_ITER(9,6)  G1_ITER(10,6) G1_ITER(11,6)
      G1_ITER(12,6) G1_ITER(13,6) G1_ITER(14,6) G1_ITER(15,6)
      G1_ITER(16,6) G1_ITER(17,6) G1_ITER(18,6) G1_ITER(19,6)
      G1_ITER(20,6) G1_ITER(21,6) G1_ITER(22,6) G1_ITER(23,6)
      G1_ITER(24,6) G1_ITER(25,6) G1_ITER(26,6) G1_ITER(27,6)
      G1_ITER(28,6) G1_ITER(29,4) G1_ITER(30,2) G1_ITER(31,0)
#undef G1_ITER
    }
#undef G1_ISSUE

    // ---- epilogue (exchange writes via sc1) ----
    {
      const bool emit = (t < 29);
      if (!g2){
        const uint32_t kk0 = K[2], kk1 = K[3];
        ushort* sp1u = (ushort*)sp1bn;
#pragma unroll
        for (int i2 = 0; i2 < 4; ++i2){
          const int rloc = (w<<4) + (sl<<2) + i2;
          float v = acc0[i2] + acc1[i2];
          float sm = 0.f;
#pragma unroll
          for (int k2 = 0; k2 < 10; ++k2)
            sm = fmaf(AUX[rloc*10 + k2], W1epi[lr*10 + k2], sm);
          v += b2s[lr] + sm;
          const float s = Sst[(rloc<<4) + lr];
          float nv = s + DTv*(-s + v);
          nv = fminf(fmaxf(nv, 0.f), 1.f);
          Sst[(rloc<<4) + lr] = nv;
          if (emit){
            const int R = (sub<<7) + rloc;
            const int e = (R << 10) + cb + lr;
            uint32_t x0 = 0u, x1 = (uint32_t)e;
            tf2x32(kk0, kk1, x0, x1);
            const bool sp = (u01(x0 ^ x1) < nv);
            const int hh = (int)f2bf(nv);
            const int ll = (int)f2bf(nv - bf2f((ushort)hh));
            const int hp = __shfl_down(hh, 1);
            const int lp = __shfl_down(ll, 1);
            if (!(lr & 1)){
              st_u32_sc((uint*)&ahn[e], (uint)(ushort)hh | ((uint)(ushort)hp << 16));
              st_u32_sc((uint*)&aln[e], (uint)(ushort)ll | ((uint)(ushort)lp << 16));
            }
            const unsigned long long bt = __ballot(sp ? 1 : 0);
            if (lr == 0) st_u16_sc(&sp1u[R*64 + (cb>>4)], (uint)((bt >> (sl<<4)) & 0xFFFFu));
          }
        }
      } else {
        const uint32_t kk0 = K[4], kk1 = K[5];
        ushort* sp2u = (ushort*)sp2bn;
#pragma unroll
        for (int i2 = 0; i2 < 4; ++i2){
          const int rloc = (w<<4) + (sl<<2) + i2;
          float v = acc0[i2] + acc1[i2] + acc2[i2];
          v += AUX[(rloc<<4) + lr];
          const float s = Sst[(rloc<<4) + lr];
          float nv = s + DTv*(-s + v);
          nv = fminf(fmaxf(nv, 0.f), 1.f);
          Sst[(rloc<<4) + lr] = nv;
          if (emit){
            const int R = (sub<<7) + rloc;
            const int e = (R << 10) + cb + lr;
            uint32_t x0 = 0u, x1 = (uint32_t)e;
            tf2x32(kk0, kk1, x0, x1);
            const bool sp = (u01(x0 ^ x1) < nv);
            const unsigned long long bt = __ballot(sp ? 1 : 0);
            if (lr == 0) st_u16_sc(&sp2u[R*64 + (cb>>4)], (uint)((bt >> (sl<<4)) & 0xFFFFu));
          }
        }
      }
    }

    asm volatile("s_waitcnt vmcnt(0)" ::: "memory");
    __syncthreads();
    if (tid == 0 && t < 29) arrive(xbar, g2 ? cB : cA, grp, (unsigned)(t+1));
  }

  // ======== final output ========
  __syncthreads();
  for (int idx = tid; idx < 2048; idx += 512){
    const int r = (sub<<7) + (idx >> 4);
    const int c = cb + (idx & 15);
    out[(g2 ? 264704 : 2560) + (r << 10) + c] = Sst[idx];
  }
  if (g2 && tid < 20) out[(r0s + tid/10)*10 + (tid%10)] = s0st[tid];
}

// ---------------- host ----------------
extern "C" void kernel_launch(void* const* d_in, const int* in_sizes, int n_in,
                              void* d_out, int out_size, void* d_ws, size_t ws_size,
                              hipStream_t stream)
{
  const float* data = (const float*)d_in[0];
  const float* s0i  = (const float*)d_in[1];
  const float* s1i  = (const float*)d_in[2];
  const float* s2i  = (const float*)d_in[3];
  const float* b0   = (const float*)d_in[5];
  const float* W1   = (const float*)d_in[6];
  const float* W2   = (const float*)d_in[7];
  const float* b2   = (const float*)d_in[8];
  const float* W3   = (const float*)d_in[9];
  const float* W4   = (const float*)d_in[10];
  const float* b4   = (const float*)d_in[11];
  float* out = (float*)d_out;
  float* ws  = (float*)d_ws;

  // ws layout (float offsets), ~10.6 MB
  float* sp0A = ws + 0;           // 2560
  float* sp0B = ws + 2560;        // 2560
  float* D2   = ws + 5120;        // 262144
  float* Pd2  = ws + 267264;      // 1835008
  ushort* ahA = (ushort*)(ws + 2102272);   // 262144 ushorts each
  ushort* ahB = (ushort*)(ws + 2233344);
  ushort* alA = (ushort*)(ws + 2364416);
  ushort* alB = (ushort*)(ws + 2495488);
  unsigned* sp1bA = (unsigned*)(ws + 2626560);  // 8192 uints each (32KB)
  unsigned* sp1bB = (unsigned*)(ws + 2634752);
  unsigned* sp2bA = (unsigned*)(ws + 2642944);
  unsigned* sp2bB = (unsigned*)(ws + 2651136);
  unsigned* bar   = (unsigned*)(ws + 2659328);  // xbar(1024B) + cA(+1024) + cB(+1280)

  hipMemsetAsync(bar, 0, 2048, stream);
  d2p_kernel<<<448,256,0,stream>>>(data, W4, Pd2);
  d2r_kernel<<<256,256,0,stream>>>(Pd2, b4, D2);
  persist_kernel<<<256,512,149504,stream>>>(
      data, s0i, s1i, s2i, W1, W2, W3, b0, b2, D2,
      sp0A, sp0B, sp1bA, sp1bB, sp2bA, sp2bB,
      ahA, ahB, alA, alB, out, bar);
}

// Round 17
// 434.395 us; speedup vs baseline: 1.5029x; 1.0759x over previous
//
#include <hip/hip_runtime.h>
#include <stdint.h>

#define DTv 0.2f

typedef __attribute__((ext_vector_type(8))) short short8;
typedef __attribute__((ext_vector_type(4))) float f32x4;
#define MFMA16(A,B,C) __builtin_amdgcn_mfma_f32_16x16x32_bf16(A,B,C,0,0,0)
#define GLOAD16(gp, lp) __builtin_amdgcn_global_load_lds( \
    (const __attribute__((address_space(1))) void*)(gp), \
    (__attribute__((address_space(3))) void*)(lp), 16, 0, 0)

// ---------------- sc0/sc1 write-through stores (visible at L3 w/o wbl2) ----------------
__device__ __forceinline__ void st_u16_sc(ushort* p, uint v){
  asm volatile("global_store_short %0, %1, off sc0 sc1" :: "v"(p), "v"(v) : "memory");
}
__device__ __forceinline__ void st_u32_sc(uint* p, uint v){
  asm volatile("global_store_dword %0, %1, off sc0 sc1" :: "v"(p), "v"(v) : "memory");
}
__device__ __forceinline__ void st_f32_sc(float* p, float v){
  asm volatile("global_store_dword %0, %1, off sc0 sc1" :: "v"(p), "v"(v) : "memory");
}

// ---------------- threefry2x32, bit-exact to JAX (partitionable) ----------------
__device__ __forceinline__ uint32_t rotl32(uint32_t v, uint32_t r){ return (v<<r)|(v>>(32u-r)); }

__device__ __forceinline__ void tf2x32(uint32_t k0, uint32_t k1, uint32_t& x0, uint32_t& x1){
  const uint32_t k2 = k0 ^ k1 ^ 0x1BD11BDAu;
  x0 += k0; x1 += k1;
#define RND(r) { x0 += x1; x1 = rotl32(x1,(r)); x1 ^= x0; }
  RND(13u) RND(15u) RND(26u) RND(6u)
  x0 += k1; x1 += k2 + 1u;
  RND(17u) RND(29u) RND(16u) RND(24u)
  x0 += k2; x1 += k0 + 2u;
  RND(13u) RND(15u) RND(26u) RND(6u)
  x0 += k0; x1 += k1 + 3u;
  RND(17u) RND(29u) RND(16u) RND(24u)
  x0 += k1; x1 += k2 + 4u;
  RND(13u) RND(15u) RND(26u) RND(6u)
  x0 += k2; x1 += k0 + 5u;
#undef RND
}

__device__ __forceinline__ float u01(uint32_t bits){
  return __uint_as_float((bits >> 9) | 0x3f800000u) - 1.0f;
}

__device__ __forceinline__ void step_keys(int t, uint32_t* K){
  uint32_t c0 = 0u, c1 = (uint32_t)t;
  tf2x32(0u, 42u, c0, c1);
#pragma unroll
  for (int i = 0; i < 3; ++i){
    uint32_t a = 0u, b = (uint32_t)i;
    tf2x32(c0, c1, a, b);
    K[2*i] = a; K[2*i+1] = b;
  }
}

__device__ __forceinline__ ushort f2bf(float f){
  uint32_t u = __float_as_uint(f);
  u += 0x7fffu + ((u >> 16) & 1u);
  return (ushort)(u >> 16);
}
__device__ __forceinline__ float bf2f(ushort h){ return __uint_as_float(((uint32_t)h) << 16); }

// ---------------- D2 = data @ W4^T + b4 (once per launch) ----------------
__global__ __launch_bounds__(256) void d2p_kernel(
    const float* __restrict__ data, const float* __restrict__ W4, float* __restrict__ Pd2)
{
  __shared__ float As[16][64];
  __shared__ float Bs[16][64];
  const int tb = blockIdx.x / 7;
  const int ch = blockIdx.x % 7;
  const int kb = ch * 112;
  const int R0 = (tb >> 4) << 6;
  const int C0 = (tb & 15) << 6;
  const int tid = threadIdx.x;
  const int ty = tid >> 4, tx = tid & 15;
  const int mA = tid >> 2, kqA = (tid & 3) << 2;
  float acc[4][4] = {{0.f}};
  for (int kk = 0; kk < 112; kk += 16){
    const float4 a = *(const float4*)&data[(R0+mA)*784 + kb + kk + kqA];
    As[kqA+0][mA]=a.x; As[kqA+1][mA]=a.y; As[kqA+2][mA]=a.z; As[kqA+3][mA]=a.w;
    const float4 b = *(const float4*)&W4[(C0+mA)*784 + kb + kk + kqA];
    Bs[kqA+0][mA]=b.x; Bs[kqA+1][mA]=b.y; Bs[kqA+2][mA]=b.z; Bs[kqA+3][mA]=b.w;
    __syncthreads();
#pragma unroll
    for (int k=0;k<16;k++){
      const float4 av = *(const float4*)&As[k][ty<<2];
      const float4 bv = *(const float4*)&Bs[k][tx<<2];
      acc[0][0]=fmaf(av.x,bv.x,acc[0][0]); acc[0][1]=fmaf(av.x,bv.y,acc[0][1]);
      acc[0][2]=fmaf(av.x,bv.z,acc[0][2]); acc[0][3]=fmaf(av.x,bv.w,acc[0][3]);
      acc[1][0]=fmaf(av.y,bv.x,acc[1][0]); acc[1][1]=fmaf(av.y,bv.y,acc[1][1]);
      acc[1][2]=fmaf(av.y,bv.z,acc[1][2]); acc[1][3]=fmaf(av.y,bv.w,acc[1][3]);
      acc[2][0]=fmaf(av.z,bv.x,acc[2][0]); acc[2][1]=fmaf(av.z,bv.y,acc[2][1]);
      acc[2][2]=fmaf(av.z,bv.z,acc[2][2]); acc[2][3]=fmaf(av.z,bv.w,acc[2][3]);
      acc[3][0]=fmaf(av.w,bv.x,acc[3][0]); acc[3][1]=fmaf(av.w,bv.y,acc[3][1]);
      acc[3][2]=fmaf(av.w,bv.z,acc[3][2]); acc[3][3]=fmaf(av.w,bv.w,acc[3][3]);
    }
    __syncthreads();
  }
  float* P = Pd2 + ch*262144;
#pragma unroll
  for (int i=0;i<4;i++){
    const int r = R0 + (ty<<2) + i;
    float4 o; float* op=(float*)&o;
#pragma unroll
    for (int j=0;j<4;j++) op[j] = acc[i][j];
    *(float4*)&P[r*1024 + C0 + (tx<<2)] = o;
  }
}

__global__ __launch_bounds__(256) void d2r_kernel(
    const float* __restrict__ Pd2, const float* __restrict__ b4, float* __restrict__ D2)
{
  const int e = (blockIdx.x*256 + threadIdx.x) << 2;
  float4 acc = *(const float4*)&Pd2[e];
#pragma unroll
  for (int p = 1; p < 7; ++p){
    const float4 q = *(const float4*)&Pd2[p*262144 + e];
    acc.x += q.x; acc.y += q.y; acc.z += q.z; acc.w += q.w;
  }
  const float4 bb = *(const float4*)&b4[e & 1023];
  acc.x += bb.x; acc.y += bb.y; acc.z += bb.z; acc.w += bb.w;
  *(float4*)&D2[e] = acc;
}

// ---------------- pairwise alternating sync (relaxed; sc1 data stores) ----------------
__device__ __forceinline__ void arrive(unsigned* xbar, unsigned* cnt, int grp, unsigned a){
  const unsigned old = __hip_atomic_fetch_add(&xbar[grp << 5], 1u,
                        __ATOMIC_RELAXED, __HIP_MEMORY_SCOPE_AGENT);
  if (old == a*32u + 31u)
    __hip_atomic_fetch_add(cnt, 1u, __ATOMIC_RELAXED, __HIP_MEMORY_SCOPE_AGENT);
}
__device__ __forceinline__ void spinwait(unsigned* cnt, unsigned target){
  unsigned it = 0;
  while (__hip_atomic_load(cnt, __ATOMIC_RELAXED, __HIP_MEMORY_SCOPE_AGENT) < target){
    __builtin_amdgcn_s_sleep(2);
    if (++it > (1u<<26)) break;
  }
  __builtin_amdgcn_fence(__ATOMIC_ACQUIRE, "agent");   // one inv per step
}

// ---------------- persistent kernel (r13 structure; s0-duty single-pass) ----------------
__global__ __launch_bounds__(512) void persist_kernel(
    const float* __restrict__ data, const float* __restrict__ s0i,
    const float* __restrict__ s1i, const float* __restrict__ s2i,
    const float* __restrict__ W1g, const float* __restrict__ W2,
    const float* __restrict__ W3, const float* __restrict__ b0g,
    const float* __restrict__ b2g, const float* __restrict__ D2,
    float* __restrict__ sp0A, float* __restrict__ sp0B,
    unsigned* __restrict__ sp1bA, unsigned* __restrict__ sp1bB,
    unsigned* __restrict__ sp2bA, unsigned* __restrict__ sp2bB,
    ushort* __restrict__ ahA, ushort* __restrict__ ahB,
    ushort* __restrict__ alA, ushort* __restrict__ alB,
    float* __restrict__ out, unsigned* __restrict__ bar)
{
  extern __shared__ char lds[];
  short* Bh   = (short*)lds;                 // [kg 128][col 16][8] shorts = 32KB
  short* Bl   = (short*)(lds + 32768);       // 32KB
  short* Abuf = (short*)(lds + 65536);       // 64KB (G1 staging only)
  float* Sst  = (float*)(lds + 131072);      // [128][16] = 8KB
  float* AUX  = (float*)(lds + 139264);      // 8KB: g2? D2 slice : sp0 slice
  float* MISC = (float*)(lds + 147456);      // 2KB
  uint32_t* K  = (uint32_t*)MISC;            // 6
  float* b0s   = MISC + 8;                   // 10
  float* s0st  = MISC + 18;                  // 20
  float* s0red = MISC + 40;                  // 160 ([rr 2][wave 8][c 10])
  float* b2s   = MISC + 200;                 // 16
  float* W1epi = MISC + 216;                 // 160

  unsigned* xbar = bar;          // 8 counters, 128B apart
  unsigned* cA   = bar + 256;    // G0 group completions (4/iter)
  unsigned* cB   = bar + 320;    // G1 group completions (4/iter)

  const int bid = blockIdx.x, tid = threadIdx.x;
  const int grp = bid & 7;
  const int g2 = (bid >> 2) & 1, sub = (bid >> 1) & 1;
  const int coltile = ((bid & 1) << 5) + (bid >> 3);
  const int cb = coltile << 4;
  const int w = tid >> 6, lane = tid & 63, lr = lane & 15, sl = lane >> 4;
  const int r0s = ((coltile << 1) + sub) << 1;    // G1's two s0 rows

  // ======== preamble ========
  { // B slice (16 cols of W2/W3), split hi/lo bf16
    const float* Wsrc = g2 ? W3 : W2;
    const int row = tid >> 5, seg = tid & 31;
    const float* src = &Wsrc[(cb + row)*1024 + seg*32];
#pragma unroll
    for (int g = 0; g < 4; ++g){
      short8 h8, l8;
#pragma unroll
      for (int j = 0; j < 8; ++j){
        const float f = src[g*8 + j];
        const ushort hh = f2bf(f);
        h8[j] = (short)hh;
        l8[j] = (short)f2bf(f - bf2f(hh));
      }
      const int kg = seg*4 + g;
      *(short8*)&Bh[(kg<<7) + (row<<3)] = h8;
      *(short8*)&Bl[(kg<<7) + (row<<3)] = l8;
    }
  }
  for (int i = tid; i < 160; i += 512) W1epi[i] = W1g[(cb + i/10)*10 + (i%10)];
  float w1c[20];
#pragma unroll
  for (int j = 0; j < 10; ++j){
    w1c[j]      = W1g[tid*10 + j];
    w1c[10 + j] = W1g[(tid + 512)*10 + j];
  }
  {
    const float* Ssrc = g2 ? s2i : s1i;
    for (int idx = tid; idx < 2048; idx += 512){
      const int r = idx >> 4, c = idx & 15;
      Sst[idx] = Ssrc[(((sub<<7)+r)<<10) + cb + c];
    }
    if (g2){
      for (int idx = tid; idx < 2048; idx += 512){
        const int r = idx >> 4, c = idx & 15;
        AUX[idx] = D2[(((sub<<7)+r)<<10) + cb + c];
      }
    }
  }
  if (tid < 10) b0s[tid] = b0g[tid];
  if (g2 && tid < 20) s0st[tid] = s0i[(r0s + tid/10)*10 + (tid%10)];
  if (tid < 16) b2s[tid] = b2g[cb + tid];
  for (int idx = tid; idx < 784; idx += 512)
    out[526848 + bid*784 + idx] = data[bid*784 + idx];
  if (tid == 0) step_keys(0, K);
  __syncthreads();

  // ======== spikes(0): sc1 writes ========
  {
    const uint32_t kk0 = g2 ? K[4] : K[2];
    const uint32_t kk1 = g2 ? K[5] : K[3];
    ushort* sp1u = (ushort*)sp1bA;
    ushort* sp2u = (ushort*)sp2bA;
#pragma unroll
    for (int i2 = 0; i2 < 4; ++i2){
      const int rloc = (w<<4) + (sl<<2) + i2;
      const int R = (sub<<7) + rloc;
      const int e = (R << 10) + cb + lr;
      const float v = fminf(fmaxf(Sst[(rloc<<4) + lr], 0.f), 1.f);
      uint32_t x0 = 0u, x1 = (uint32_t)e;
      tf2x32(kk0, kk1, x0, x1);
      const bool sp = (u01(x0 ^ x1) < v);
      const unsigned long long bt = __ballot(sp ? 1 : 0);
      if (!g2){
        const int hh = (int)f2bf(v);
        const int ll = (int)f2bf(v - bf2f((ushort)hh));
        const int hp = __shfl_down(hh, 1);
        const int lp = __shfl_down(ll, 1);
        if (!(lr & 1)){
          st_u32_sc((uint*)&ahA[e], (uint)(ushort)hh | ((uint)(ushort)hp << 16));
          st_u32_sc((uint*)&alA[e], (uint)(ushort)ll | ((uint)(ushort)lp << 16));
        }
        if (lr == 0) st_u16_sc(&sp1u[R*64 + (cb>>4)], (uint)((bt >> (sl<<4)) & 0xFFFFu));
      } else {
        if (lr == 0) st_u16_sc(&sp2u[R*64 + (cb>>4)], (uint)((bt >> (sl<<4)) & 0xFFFFu));
      }
    }
    if (g2 && tid < 20){
      const float v = fminf(fmaxf(s0st[tid], 0.f), 1.f);
      const int e = (r0s + tid/10)*10 + (tid%10);
      uint32_t x0 = 0u, x1 = (uint32_t)e;
      tf2x32(K[0], K[1], x0, x1);
      st_f32_sc(&sp0A[e], (u01(x0 ^ x1) < v) ? 1.0f : 0.0f);
    }
  }
  asm volatile("s_waitcnt vmcnt(0)" ::: "memory");
  __syncthreads();
  if (tid == 0) arrive(xbar, g2 ? cB : cA, grp, 0u);

  // GEMM constants (r13 mapping)
  const int r0g = (sub << 7) + (w << 4);
  const int gbase = ((r0g + (lane >> 2)) << 10) + ((((lane & 3) ^ ((lane >> 2) & 3))) << 3);
  const int fragoff = (lr << 5) + ((sl ^ (lr & 3)) << 3);
  const int shl = sl << 3;
  short* AW = Abuf + (w << 12);

#pragma unroll 1
  for (int t = 0; t < 30; ++t){
    const int cur = t & 1;
    const float*    sp0c  = cur ? sp0B  : sp0A;   float*    sp0n  = cur ? sp0A  : sp0B;
    const unsigned* sp1bc = cur ? sp1bB : sp1bA;  unsigned* sp1bn = cur ? sp1bA : sp1bB;
    const unsigned* sp2bc = cur ? sp2bB : sp2bA;  unsigned* sp2bn = cur ? sp2bA : sp2bB;
    const ushort*   ahc   = cur ? ahB   : ahA;    ushort*   ahn   = cur ? ahA   : ahB;
    const ushort*   alc   = cur ? alB   : alA;    ushort*   aln   = cur ? alA   : alB;

    if (tid == 0){
      step_keys(t+1, K);
      spinwait(g2 ? cA : cB, 4u*(t+1));   // wait ONLY on the other group
    }
    __syncthreads();

    if (!g2){
      for (int idx = tid; idx < 1280; idx += 512) AUX[idx] = sp0c[sub*1280 + idx];
      __syncthreads();
    } else {
      // ---- s0 duty: both rows in one pass (1 sync) ----
      const unsigned* mrow0 = sp1bc + r0s*32;
      const unsigned* mrow1 = sp1bc + (r0s+1)*32;
      const unsigned d00 = mrow0[tid >> 5];
      const unsigned d01 = mrow0[16 + (tid >> 5)];
      const unsigned d10 = mrow1[tid >> 5];
      const unsigned d11 = mrow1[16 + (tid >> 5)];
      const float sv00 = (float)((d00 >> (tid & 31)) & 1u);
      const float sv01 = (float)((d01 >> (tid & 31)) & 1u);
      const float sv10 = (float)((d10 >> (tid & 31)) & 1u);
      const float sv11 = (float)((d11 >> (tid & 31)) & 1u);
      float a0_[10], a1_[10];
#pragma unroll
      for (int c2 = 0; c2 < 10; ++c2){
        a0_[c2] = fmaf(sv01, w1c[10 + c2], fmaf(sv00, w1c[c2], 0.f));
        a1_[c2] = fmaf(sv11, w1c[10 + c2], fmaf(sv10, w1c[c2], 0.f));
      }
#pragma unroll
      for (int c2 = 0; c2 < 10; ++c2){
        float v0 = a0_[c2], v1 = a1_[c2];
        v0 += __shfl_xor(v0, 1);  v1 += __shfl_xor(v1, 1);
        v0 += __shfl_xor(v0, 2);  v1 += __shfl_xor(v1, 2);
        v0 += __shfl_xor(v0, 4);  v1 += __shfl_xor(v1, 4);
        v0 += __shfl_xor(v0, 8);  v1 += __shfl_xor(v1, 8);
        v0 += __shfl_xor(v0, 16); v1 += __shfl_xor(v1, 16);
        v0 += __shfl_xor(v0, 32); v1 += __shfl_xor(v1, 32);
        a0_[c2] = v0; a1_[c2] = v1;
      }
      if (lane == 0){
#pragma unroll
        for (int c2 = 0; c2 < 10; ++c2){
          s0red[w*10 + c2]      = a0_[c2];
          s0red[80 + w*10 + c2] = a1_[c2];
        }
      }
      __syncthreads();
      if (tid < 20){
        const int rr = tid / 10, c2 = tid % 10;
        float sum = 0.f;
#pragma unroll
        for (int ww = 0; ww < 8; ++ww) sum += s0red[rr*80 + ww*10 + c2];
        const float s = s0st[tid];
        float nv = s + DTv*(-s + sum + b0s[c2]);
        nv = fminf(fmaxf(nv, 0.f), 1.f);
        s0st[tid] = nv;
        const int e = (r0s + rr)*10 + c2;
        uint32_t x0 = 0u, x1 = (uint32_t)e;
        tf2x32(K[0], K[1], x0, x1);
        st_f32_sc(&sp0n[e], (u01(x0 ^ x1) < nv) ? 1.0f : 0.0f);
      }
    }

    // ---- GEMM ----
    f32x4 acc0 = {0.f,0.f,0.f,0.f}, acc1 = {0.f,0.f,0.f,0.f}, acc2 = {0.f,0.f,0.f,0.f};
    if (!g2){
      // A from sp2 bit panel, unpacked in registers (bit-identical to bf16 spikes)
      const unsigned* mrow = sp2bc + (r0g + lr)*32;
      const uint4 m0 = *(const uint4*)(mrow +  0);
      const uint4 m1 = *(const uint4*)(mrow +  4);
      const uint4 m2 = *(const uint4*)(mrow +  8);
      const uint4 m3 = *(const uint4*)(mrow + 12);
      const uint4 m4 = *(const uint4*)(mrow + 16);
      const uint4 m5 = *(const uint4*)(mrow + 20);
      const uint4 m6 = *(const uint4*)(mrow + 24);
      const uint4 m7 = *(const uint4*)(mrow + 28);
#define U0(ks, DW) { \
      const unsigned b_ = ((DW) >> shl) & 0xFFu; \
      short8 a8; \
      a8[0]=(short)(((b_    )&1)?0x3F80:0); a8[1]=(short)(((b_>>1)&1)?0x3F80:0); \
      a8[2]=(short)(((b_>>2)&1)?0x3F80:0); a8[3]=(short)(((b_>>3)&1)?0x3F80:0); \
      a8[4]=(short)(((b_>>4)&1)?0x3F80:0); a8[5]=(short)(((b_>>5)&1)?0x3F80:0); \
      a8[6]=(short)(((b_>>6)&1)?0x3F80:0); a8[7]=(short)(((b_>>7)&1)?0x3F80:0); \
      const int ib = ((((ks)<<2)+sl)<<7) + (lr<<3); \
      const short8 bh8 = *(const short8*)(Bh + ib); \
      const short8 bl8 = *(const short8*)(Bl + ib); \
      acc0 = MFMA16(a8, bh8, acc0); \
      acc1 = MFMA16(a8, bl8, acc1); }
      U0(0,m0.x)  U0(1,m0.y)  U0(2,m0.z)  U0(3,m0.w)
      U0(4,m1.x)  U0(5,m1.y)  U0(6,m1.z)  U0(7,m1.w)
      U0(8,m2.x)  U0(9,m2.y)  U0(10,m2.z) U0(11,m2.w)
      U0(12,m3.x) U0(13,m3.y) U0(14,m3.z) U0(15,m3.w)
      U0(16,m4.x) U0(17,m4.y) U0(18,m4.z) U0(19,m4.w)
      U0(20,m5.x) U0(21,m5.y) U0(22,m5.z) U0(23,m5.w)
      U0(24,m6.x) U0(25,m6.y) U0(26,m6.z) U0(27,m6.w)
      U0(28,m7.x) U0(29,m7.y) U0(30,m7.z) U0(31,m7.w)
#undef U0
    } else {
      const short* Ah0 = (const short*)ahc + gbase;
      const short* Al0 = (const short*)alc + gbase;
#define G1_ISSUE(c) { GLOAD16(Ah0 + ((c)<<5), AW + (((c)&3)<<10)); \
                      GLOAD16(Al0 + ((c)<<5), AW + (((c)&3)<<10) + 512); }
#define G1_ITER(c, vm) { \
      asm volatile("s_waitcnt vmcnt(" #vm ")" ::: "memory"); \
      __builtin_amdgcn_sched_barrier(0); \
      const short8 h8  = *(const short8*)(AW + (((c)&3)<<10) + fragoff); \
      const short8 l8  = *(const short8*)(AW + (((c)&3)<<10) + 512 + fragoff); \
      const int ib = ((((c)<<2)+sl)<<7) + (lr<<3); \
      const short8 bh8 = *(const short8*)(Bh + ib); \
      const short8 bl8 = *(const short8*)(Bl + ib); \
      acc0 = MFMA16(h8, bh8, acc0); \
      acc1 = MFMA16(h8, bl8, acc1); \
      acc2 = MFMA16(l8, bh8, acc2); \
      __builtin_amdgcn_sched_barrier(0); \
      if ((c) < 28) G1_ISSUE((c)+4) }
      G1_ISSUE(0) G1_ISSUE(1) G1_ISSUE(2) G1_ISSUE(3)
      G1_ITER(0,6)  G1_ITER(1,6)  G1_ITER(2,6)  G1_ITER(3,6)
      G1_ITER(4,6)  G1_ITER(5,6)  G1_ITER(6,6)  G1_ITER(7,6)
      G1_ITER(8,6)  G1_ITER(9,6)  G1_ITER(10,6) G1_ITER(11,6)
      G1_ITER(12,6) G1_ITER(13,6) G1_ITER(14,6) G1_ITER(15,6)
      G1_ITER(16,6) G1_ITER(17,6) G1_ITER(18,6) G1_ITER(19,6)
      G1_ITER(20,6) G1_ITER(21,6) G1_ITER(22,6) G1_ITER(23,6)
      G1_ITER(24,6) G1_ITER(25,6) G1_ITER(26,6) G1_ITER(27,6)
      G1_ITER(28,6) G1_ITER(29,4) G1_ITER(30,2) G1_ITER(31,0)
#undef G1_ITER
#undef G1_ISSUE
    }

    // ---- epilogue (exchange writes via sc1) ----
    {
      const bool emit = (t < 29);
      if (!g2){
        const uint32_t kk0 = K[2], kk1 = K[3];
        ushort* sp1u = (ushort*)sp1bn;
#pragma unroll
        for (int i2 = 0; i2 < 4; ++i2){
          const int rloc = (w<<4) + (sl<<2) + i2;
          float v = acc0[i2] + acc1[i2];
          float sm = 0.f;
#pragma unroll
          for (int k2 = 0; k2 < 10; ++k2)
            sm = fmaf(AUX[rloc*10 + k2], W1epi[lr*10 + k2], sm);
          v += b2s[lr] + sm;
          const float s = Sst[(rloc<<4) + lr];
          float nv = s + DTv*(-s + v);
          nv = fminf(fmaxf(nv, 0.f), 1.f);
          Sst[(rloc<<4) + lr] = nv;
          if (emit){
            const int R = (sub<<7) + rloc;
            const int e = (R << 10) + cb + lr;
            uint32_t x0 = 0u, x1 = (uint32_t)e;
            tf2x32(kk0, kk1, x0, x1);
            const bool sp = (u01(x0 ^ x1) < nv);
            const int hh = (int)f2bf(nv);
            const int ll = (int)f2bf(nv - bf2f((ushort)hh));
            const int hp = __shfl_down(hh, 1);
            const int lp = __shfl_down(ll, 1);
            if (!(lr & 1)){
              st_u32_sc((uint*)&ahn[e], (uint)(ushort)hh | ((uint)(ushort)hp << 16));
              st_u32_sc((uint*)&aln[e], (uint)(ushort)ll | ((uint)(ushort)lp << 16));
            }
            const unsigned long long bt = __ballot(sp ? 1 : 0);
            if (lr == 0) st_u16_sc(&sp1u[R*64 + (cb>>4)], (uint)((bt >> (sl<<4)) & 0xFFFFu));
          }
        }
      } else {
        const uint32_t kk0 = K[4], kk1 = K[5];
        ushort* sp2u = (ushort*)sp2bn;
#pragma unroll
        for (int i2 = 0; i2 < 4; ++i2){
          const int rloc = (w<<4) + (sl<<2) + i2;
          float v = acc0[i2] + acc1[i2] + acc2[i2];
          v += AUX[(rloc<<4) + lr];
          const float s = Sst[(rloc<<4) + lr];
          float nv = s + DTv*(-s + v);
          nv = fminf(fmaxf(nv, 0.f), 1.f);
          Sst[(rloc<<4) + lr] = nv;
          if (emit){
            const int R = (sub<<7) + rloc;
            const int e = (R << 10) + cb + lr;
            uint32_t x0 = 0u, x1 = (uint32_t)e;
            tf2x32(kk0, kk1, x0, x1);
            const bool sp = (u01(x0 ^ x1) < nv);
            const unsigned long long bt = __ballot(sp ? 1 : 0);
            if (lr == 0) st_u16_sc(&sp2u[R*64 + (cb>>4)], (uint)((bt >> (sl<<4)) & 0xFFFFu));
          }
        }
      }
    }

    asm volatile("s_waitcnt vmcnt(0)" ::: "memory");
    __syncthreads();
    if (tid == 0 && t < 29) arrive(xbar, g2 ? cB : cA, grp, (unsigned)(t+1));
  }

  // ======== final output ========
  __syncthreads();
  for (int idx = tid; idx < 2048; idx += 512){
    const int r = (sub<<7) + (idx >> 4);
    const int c = cb + (idx & 15);
    out[(g2 ? 264704 : 2560) + (r << 10) + c] = Sst[idx];
  }
  if (g2 && tid < 20) out[(r0s + tid/10)*10 + (tid%10)] = s0st[tid];
}

// ---------------- host ----------------
extern "C" void kernel_launch(void* const* d_in, const int* in_sizes, int n_in,
                              void* d_out, int out_size, void* d_ws, size_t ws_size,
                              hipStream_t stream)
{
  const float* data = (const float*)d_in[0];
  const float* s0i  = (const float*)d_in[1];
  const float* s1i  = (const float*)d_in[2];
  const float* s2i  = (const float*)d_in[3];
  const float* b0   = (const float*)d_in[5];
  const float* W1   = (const float*)d_in[6];
  const float* W2   = (const float*)d_in[7];
  const float* b2   = (const float*)d_in[8];
  const float* W3   = (const float*)d_in[9];
  const float* W4   = (const float*)d_in[10];
  const float* b4   = (const float*)d_in[11];
  float* out = (float*)d_out;
  float* ws  = (float*)d_ws;

  // ws layout (float offsets), ~10.6 MB
  float* sp0A = ws + 0;           // 2560
  float* sp0B = ws + 2560;        // 2560
  float* D2   = ws + 5120;        // 262144
  float* Pd2  = ws + 267264;      // 1835008
  ushort* ahA = (ushort*)(ws + 2102272);   // 262144 ushorts each
  ushort* ahB = (ushort*)(ws + 2233344);
  ushort* alA = (ushort*)(ws + 2364416);
  ushort* alB = (ushort*)(ws + 2495488);
  unsigned* sp1bA = (unsigned*)(ws + 2626560);  // 8192 uints each (32KB)
  unsigned* sp1bB = (unsigned*)(ws + 2634752);
  unsigned* sp2bA = (unsigned*)(ws + 2642944);
  unsigned* sp2bB = (unsigned*)(ws + 2651136);
  unsigned* bar   = (unsigned*)(ws + 2659328);  // xbar(1024B) + cA(+1024) + cB(+1280)

  hipMemsetAsync(bar, 0, 2048, stream);
  d2p_kernel<<<448,256,0,stream>>>(data, W4, Pd2);
  d2r_kernel<<<256,256,0,stream>>>(Pd2, b4, D2);
  persist_kernel<<<256,512,149504,stream>>>(
      data, s0i, s1i, s2i, W1, W2, W3, b0, b2, D2,
      sp0A, sp0B, sp1bA, sp1bB, sp2bA, sp2bB,
      ahA, ahB, alA, alB, out, bar);
}